// Round 2
// baseline (426.546 us; speedup 1.0000x reference)
//
#include <hip/hip_runtime.h>
#include <hip/hip_cooperative_groups.h>
#include <math.h>

namespace cg = cooperative_groups;

// Problem constants (shapes fixed by setup_inputs)
#define B     4
#define DIM   256
#define NP    128   // nPnt
#define NS    144   // 12*12 unique token_init rows per batch
#define HID   512   // 4*nPnt
#define NROW  576   // B*NS
#define H_OUT 120
#define W_OUT 160

__device__ __forceinline__ float gelu_exact(float x) {
    return 0.5f * x * (1.0f + erff(x * 0.70710678118654752440f));
}

// Shared-memory phase views over one 36 KB arena.
struct SmMlp {
    float xs[4][DIM];        //  4 KB ti rows
    float parA[2][4][NP];    //  4 KB Q partials (2 d-halves)
    float qs[4][NP];         //  2 KB
    float hs[4][HID];        //  8 KB
    float par[8][4][NP];     // 16 KB layer-2 partials
    float red[4][NP];        //  2 KB softmax scratch
};
struct SmFold {
    float an[NS];
    float w1p[24][48];
    float b1s[48];
    float w2s[48];
};
struct SmFin {
    float  at[NP];
    float4 par4[4][64];
    float4 rowf[64];
};

// ---------------------------------------------------------------------------
// Cooperative fused kernel: grid = 256 blocks (1/CU -> capacity check can
// never reject), 4 phases, 3 grid syncs. Phases with >256 tasks loop.
// ---------------------------------------------------------------------------
__global__ __launch_bounds__(256, 2) void k_all(
    const float* __restrict__ ti, const float* __restrict__ pt,
    const float* __restrict__ nr_w1, const float* __restrict__ nr_b1,
    const float* __restrict__ nr_w2, const float* __restrict__ nr_b2,
    const float* __restrict__ na_w1, const float* __restrict__ na_b1,
    const float* __restrict__ na_w2, const float* __restrict__ na_b2,
    const float* __restrict__ tf_w1, const float* __restrict__ tf_b1,
    const float* __restrict__ tf_w2, const float* __restrict__ tf_b2,
    float* __restrict__ nadjT, float* __restrict__ attn,
    float* __restrict__ tfb, float* __restrict__ ptT,
    float4* __restrict__ out)
{
    cg::grid_group grid = cg::this_grid();
    const int blk = blockIdx.x;
    const int t   = threadIdx.x;

    __shared__ __align__(16) char smraw[sizeof(SmMlp)];

    // ---- Phase 0: transpose point_token -> ptT[b][d][p] (blocks 0..127) ----
    if (blk < 128) {
        float (*tile)[33] = reinterpret_cast<float (*)[33]>(smraw);
        const int b   = blk >> 5;
        const int rem = blk & 31;
        const int d0  = (rem >> 2) * 32;
        const int p0  = (rem & 3) * 32;
        #pragma unroll
        for (int i = t; i < 1024; i += 256) {
            const int row = i >> 5, col = i & 31;   // row = p-local, col = d-local
            tile[row][col] = pt[(size_t)(b * NP + p0 + row) * DIM + d0 + col];
        }
        __syncthreads();
        #pragma unroll
        for (int i = t; i < 1024; i += 256) {
            const int row = i >> 5, col = i & 31;   // row = d-local, col = p-local
            ptT[(size_t)(b * DIM + d0 + row) * NP + p0 + col] = tile[col][row];
        }
    }
    __threadfence();
    grid.sync();
    __threadfence();

    // ---- Phase 1: fused Q -> layer1 -> layer2 (-> softmax), both MLPs ------
    // 288 tasks over 256 blocks.
    {
        SmMlp& s = *reinterpret_cast<SmMlp*>(smraw);
        for (int task = blk; task < 288; task += 256) {
            __syncthreads();
            const int mlp  = task / 144;
            const int tile = task % 144;
            const int g0 = tile * 4;
            const int b  = g0 / NS;
            const int n0 = g0 % NS;

            const float* __restrict__ w1 = mlp ? na_w1 : nr_w1;
            const float* __restrict__ b1 = mlp ? na_b1 : nr_b1;
            const float* __restrict__ w2 = mlp ? na_w2 : nr_w2;
            const float* __restrict__ b2 = mlp ? na_b2 : nr_b2;

            // Stage A: Q[4][128] = ti_rows @ ptT (coalesced)
            {
                const int r = t >> 6, c = t & 63;
                ((float4*)s.xs[r])[c] =
                    ((const float4*)ti)[(size_t)(g0 + r) * 64 + c];
            }
            __syncthreads();
            {
                const int pq = t & 31;          // p-quad
                const int rr = (t >> 5) & 3;    // row
                const int dh = t >> 7;          // d-half
                const float4* __restrict__ pT4 =
                    (const float4*)(ptT + (size_t)b * DIM * NP) + pq;
                float4 acc = make_float4(0.f, 0.f, 0.f, 0.f);
                #pragma unroll 8
                for (int d2 = 0; d2 < 128; ++d2) {
                    const int d = dh * 128 + d2;
                    const float4 v4 = pT4[(size_t)d * 32];
                    const float  xv = s.xs[rr][d];
                    acc.x += xv * v4.x; acc.y += xv * v4.y;
                    acc.z += xv * v4.z; acc.w += xv * v4.w;
                }
                ((float4*)s.parA[dh][rr])[pq] = acc;
            }
            __syncthreads();

            const int p  = t & 127;
            const int rh = t >> 7;              // covers rows rh and rh+2
            s.qs[rh][p]     = (s.parA[0][rh][p]     + s.parA[1][rh][p])     * 0.0625f;
            s.qs[rh + 2][p] = (s.parA[0][rh + 2][p] + s.parA[1][rh + 2][p]) * 0.0625f;
            __syncthreads();

            // Stage B: H = gelu(b1 + Q @ w1)
            {
                const int kq = t & 127;
                const int k0 = kq * 4;
                float4 acc0 = *(const float4*)(b1 + k0);
                float4 acc1 = acc0;
                const float* __restrict__ wp = w1 + k0;
                #pragma unroll 8
                for (int pp = 0; pp < NP; ++pp) {
                    const float4 w4 = *(const float4*)(wp + (size_t)pp * HID);
                    const float q0 = s.qs[rh][pp];
                    const float q1 = s.qs[rh + 2][pp];
                    acc0.x += q0*w4.x; acc0.y += q0*w4.y;
                    acc0.z += q0*w4.z; acc0.w += q0*w4.w;
                    acc1.x += q1*w4.x; acc1.y += q1*w4.y;
                    acc1.z += q1*w4.z; acc1.w += q1*w4.w;
                }
                float4 o0, o1;
                o0.x = gelu_exact(acc0.x); o0.y = gelu_exact(acc0.y);
                o0.z = gelu_exact(acc0.z); o0.w = gelu_exact(acc0.w);
                o1.x = gelu_exact(acc1.x); o1.y = gelu_exact(acc1.y);
                o1.z = gelu_exact(acc1.z); o1.w = gelu_exact(acc1.w);
                ((float4*)s.hs[rh])[kq]     = o0;
                ((float4*)s.hs[rh + 2])[kq] = o1;
            }
            __syncthreads();

            // Stage C: logits = b2 + H @ w2 (k split over 8 groups)
            {
                const int pq = t & 31;
                const int p0 = pq * 4;
                const int kg = t >> 5;
                float4 a0 = make_float4(0.f,0.f,0.f,0.f);
                float4 a1 = a0, a2 = a0, a3 = a0;
                const float4* __restrict__ w24 = (const float4*)(w2 + p0);
                #pragma unroll 8
                for (int i = 0; i < 64; ++i) {
                    const int k = kg * 64 + i;
                    const float4 w4 = w24[(size_t)k * 32];
                    const float h0 = s.hs[0][k], h1 = s.hs[1][k];
                    const float h2 = s.hs[2][k], h3 = s.hs[3][k];
                    a0.x += h0*w4.x; a0.y += h0*w4.y; a0.z += h0*w4.z; a0.w += h0*w4.w;
                    a1.x += h1*w4.x; a1.y += h1*w4.y; a1.z += h1*w4.z; a1.w += h1*w4.w;
                    a2.x += h2*w4.x; a2.y += h2*w4.y; a2.z += h2*w4.z; a2.w += h2*w4.w;
                    a3.x += h3*w4.x; a3.y += h3*w4.y; a3.z += h3*w4.z; a3.w += h3*w4.w;
                }
                ((float4*)s.par[kg][0])[pq] = a0;
                ((float4*)s.par[kg][1])[pq] = a1;
                ((float4*)s.par[kg][2])[pq] = a2;
                ((float4*)s.par[kg][3])[pq] = a3;
            }
            __syncthreads();

            // Reduce + emit
            float lg0 = b2[p], lg1 = lg0;
            #pragma unroll
            for (int kg = 0; kg < 8; ++kg) {
                lg0 += s.par[kg][rh][p];
                lg1 += s.par[kg][rh + 2][p];
            }

            if (mlp == 0) {
                float* __restrict__ dst = nadjT + (size_t)(b * NP + p) * NS + n0;
                dst[rh]     = lg0;
                dst[rh + 2] = lg1;
            } else {
                s.red[rh][p] = lg0; s.red[rh + 2][p] = lg1;
                __syncthreads();
                for (int sw = 64; sw > 0; sw >>= 1) {
                    if (p < sw) {
                        s.red[rh][p]     = fmaxf(s.red[rh][p],     s.red[rh][p + sw]);
                        s.red[rh + 2][p] = fmaxf(s.red[rh + 2][p], s.red[rh + 2][p + sw]);
                    }
                    __syncthreads();
                }
                const float m0 = s.red[rh][0], m1 = s.red[rh + 2][0];
                __syncthreads();
                const float e0 = expf(lg0 - m0), e1 = expf(lg1 - m1);
                s.red[rh][p] = e0; s.red[rh + 2][p] = e1;
                __syncthreads();
                for (int sw = 64; sw > 0; sw >>= 1) {
                    if (p < sw) {
                        s.red[rh][p]     += s.red[rh][p + sw];
                        s.red[rh + 2][p] += s.red[rh + 2][p + sw];
                    }
                    __syncthreads();
                }
                attn[(size_t)(g0 + rh) * NP + p]     = e0 / s.red[rh][0];
                attn[(size_t)(g0 + rh + 2) * NP + p] = e1 / s.red[rh + 2][0];
            }
        }
    }
    __threadfence();
    grid.sync();
    __threadfence();

    // ---- Phase 2: fold (node einsums + tf MLP), 512 tasks ------------------
    {
        SmFold& s = *reinterpret_cast<SmFold*>(smraw);
        // weights are task-invariant: stage once
        if (t >= 192 && t < 240) {
            const int k = t - 192;
            s.b1s[k] = tf_b1[k];
            s.w2s[k] = tf_w2[k];
        }
        for (int i = t; i < 24 * 48; i += 256) {
            const int m = i / 48, k = i - m * 48;
            s.w1p[m][k] = tf_w1[(2 * m) * 48 + k] + tf_w1[(2 * m + 1) * 48 + k];
        }
        for (int task = blk; task < 512; task += 256) {
            __syncthreads();
            const int b = task >> 7;
            const int p = task & 127;
            if (t < 36) {   // 144 floats = 36 float4
                ((float4*)s.an)[t] =
                    ((const float4*)(nadjT + (size_t)(b * NP + p) * NS))[t];
            }
            __syncthreads();

            const int d = t;
            const float* __restrict__ tb = ti + (size_t)b * NS * DIM + d;
            float v[24];
            #pragma unroll
            for (int m = 0; m < 24; ++m) v[m] = 0.f;
            #pragma unroll
            for (int y = 0; y < 12; ++y) {
                #pragma unroll
                for (int x = 0; x < 12; ++x) {
                    const int n = y * 12 + x;
                    const float tv = tb[n * DIM];
                    const float a  = s.an[n];
                    v[y]      += a * tv;   // node_w: m=y
                    v[12 + x] += a * tv;   // node_h: m=12+x
                }
            }
            const float c = 0.40824829046386301637f;  // 2/sqrt(24)
            #pragma unroll
            for (int m = 0; m < 24; ++m) v[m] *= c;

            float acc = tf_b2[0];
            for (int k = 0; k < 48; ++k) {
                float tt = s.b1s[k];
                #pragma unroll
                for (int m = 0; m < 24; ++m) tt += v[m] * s.w1p[m][k];
                acc += gelu_exact(tt) * s.w2s[k];
            }
            tfb[(size_t)(b * NP + p) * DIM + d] = acc;
        }
    }
    __threadfence();
    grid.sync();
    __threadfence();

    // ---- Phase 3: final attn@tf + residual + scatter, 576 row-tasks --------
    {
        SmFin& s = *reinterpret_cast<SmFin*>(smraw);
        const int dq = t & 63;
        const int pg = t >> 6;
        for (int g = blk; g < NROW; g += 256) {
            __syncthreads();
            const int b = g / NS;
            const int n = g % NS;

            if (t < NP) s.at[t] = attn[(size_t)g * NP + t];
            __syncthreads();

            const float4* __restrict__ tp =
                (const float4*)tfb + (size_t)b * NP * 64 + dq;
            float4 acc = make_float4(0.f, 0.f, 0.f, 0.f);
            #pragma unroll 8
            for (int i = 0; i < 32; ++i) {
                const int pp = pg * 32 + i;
                const float  a  = s.at[pp];
                const float4 tv = tp[(size_t)pp * 64];
                acc.x += a * tv.x; acc.y += a * tv.y;
                acc.z += a * tv.z; acc.w += a * tv.w;
            }
            s.par4[pg][dq] = acc;
            __syncthreads();

            if (t < 64) {
                float4 sv = s.par4[0][t];
                const float4 s1 = s.par4[1][t], s2 = s.par4[2][t], s3 = s.par4[3][t];
                const float4 tiv = ((const float4*)ti)[(size_t)g * 64 + t];
                sv.x += s1.x + s2.x + s3.x + tiv.x;
                sv.y += s1.y + s2.y + s3.y + tiv.y;
                sv.z += s1.z + s2.z + s3.z + tiv.z;
                sv.w += s1.w + s2.w + s3.w + tiv.w;
                s.rowf[t] = sv;
            }
            __syncthreads();

            // scatter full row: h in [10y,10y+10), w in [ceil(40x/3), ceil(40(x+1)/3))
            const int y = n / 12, x = n % 12;
            const int w_lo = (40 * x + 2) / 3;
            const int w_hi = (40 * x + 42) / 3;
            const float4 val = s.rowf[dq];
            const int h0 = 10 * y;
            for (int h = h0; h < h0 + 10; ++h) {
                float4* __restrict__ orow =
                    out + (size_t)((b * H_OUT + h) * W_OUT) * 64 + dq;
                for (int w = w_lo + pg; w < w_hi; w += 4) {
                    orow[(size_t)w * 64] = val;
                }
            }
        }
    }
}

// ===========================================================================
// Fallback: verbatim verified 4-kernel path (round-0 baseline, 170 us).
// ===========================================================================
__global__ __launch_bounds__(256) void k_t(
    const float* __restrict__ pt, float* __restrict__ ptT)
{
    const int bid = blockIdx.x;
    const int b   = bid >> 5;
    const int rem = bid & 31;
    const int d0  = (rem >> 2) * 32;
    const int p0  = (rem & 3) * 32;
    const int t   = threadIdx.x;
    __shared__ float tile[32][33];

    #pragma unroll
    for (int i = t; i < 1024; i += 256) {
        const int row = i >> 5, col = i & 31;
        tile[row][col] = pt[(size_t)(b * NP + p0 + row) * DIM + d0 + col];
    }
    __syncthreads();
    #pragma unroll
    for (int i = t; i < 1024; i += 256) {
        const int row = i >> 5, col = i & 31;
        ptT[(size_t)(b * DIM + d0 + row) * NP + p0 + col] = tile[col][row];
    }
}

__global__ __launch_bounds__(256) void k_mlp(
    const float* __restrict__ ti, const float* __restrict__ ptT,
    const float* __restrict__ nr_w1, const float* __restrict__ nr_b1,
    const float* __restrict__ nr_w2, const float* __restrict__ nr_b2,
    const float* __restrict__ na_w1, const float* __restrict__ na_b1,
    const float* __restrict__ na_w2, const float* __restrict__ na_b2,
    float* __restrict__ nadjT, float* __restrict__ attn)
{
    const int mlp  = blockIdx.x / 144;
    const int tile = blockIdx.x % 144;
    const int g0 = tile * 4;
    const int b  = g0 / NS;
    const int n0 = g0 % NS;
    const int t  = threadIdx.x;

    const float* __restrict__ w1 = mlp ? na_w1 : nr_w1;
    const float* __restrict__ b1 = mlp ? na_b1 : nr_b1;
    const float* __restrict__ w2 = mlp ? na_w2 : nr_w2;
    const float* __restrict__ b2 = mlp ? na_b2 : nr_b2;

    __shared__ float xs[4][DIM];
    __shared__ float parA[2][4][NP];
    __shared__ float qs[4][NP];
    __shared__ float hs[4][HID];
    __shared__ float par[8][4][NP];
    __shared__ float red[4][NP];

    {
        const int r = t >> 6, c = t & 63;
        ((float4*)xs[r])[c] = ((const float4*)ti)[(size_t)(g0 + r) * 64 + c];
    }
    __syncthreads();

    {
        const int pq = t & 31;
        const int rr = (t >> 5) & 3;
        const int dh = t >> 7;
        const float4* __restrict__ pT4 =
            (const float4*)(ptT + (size_t)b * DIM * NP) + pq;
        float4 acc = make_float4(0.f, 0.f, 0.f, 0.f);
        #pragma unroll 8
        for (int d2 = 0; d2 < 128; ++d2) {
            const int d = dh * 128 + d2;
            const float4 v4 = pT4[(size_t)d * 32];
            const float  xv = xs[rr][d];
            acc.x += xv * v4.x; acc.y += xv * v4.y;
            acc.z += xv * v4.z; acc.w += xv * v4.w;
        }
        ((float4*)parA[dh][rr])[pq] = acc;
    }
    __syncthreads();

    const int p  = t & 127;
    const int rh = t >> 7;
    qs[rh][p]     = (parA[0][rh][p]     + parA[1][rh][p])     * 0.0625f;
    qs[rh + 2][p] = (parA[0][rh + 2][p] + parA[1][rh + 2][p]) * 0.0625f;
    __syncthreads();

    {
        const int kq = t & 127;
        const int k0 = kq * 4;
        float4 acc0 = *(const float4*)(b1 + k0);
        float4 acc1 = acc0;
        const float* __restrict__ wp = w1 + k0;
        #pragma unroll 8
        for (int pp = 0; pp < NP; ++pp) {
            const float4 w4 = *(const float4*)(wp + (size_t)pp * HID);
            const float q0 = qs[rh][pp];
            const float q1 = qs[rh + 2][pp];
            acc0.x += q0*w4.x; acc0.y += q0*w4.y;
            acc0.z += q0*w4.z; acc0.w += q0*w4.w;
            acc1.x += q1*w4.x; acc1.y += q1*w4.y;
            acc1.z += q1*w4.z; acc1.w += q1*w4.w;
        }
        float4 o0, o1;
        o0.x = gelu_exact(acc0.x); o0.y = gelu_exact(acc0.y);
        o0.z = gelu_exact(acc0.z); o0.w = gelu_exact(acc0.w);
        o1.x = gelu_exact(acc1.x); o1.y = gelu_exact(acc1.y);
        o1.z = gelu_exact(acc1.z); o1.w = gelu_exact(acc1.w);
        ((float4*)hs[rh])[kq]     = o0;
        ((float4*)hs[rh + 2])[kq] = o1;
    }
    __syncthreads();

    {
        const int pq = t & 31;
        const int p0 = pq * 4;
        const int kg = t >> 5;
        float4 a0 = make_float4(0.f,0.f,0.f,0.f);
        float4 a1 = a0, a2 = a0, a3 = a0;
        const float4* __restrict__ w24 = (const float4*)(w2 + p0);
        #pragma unroll 8
        for (int i = 0; i < 64; ++i) {
            const int k = kg * 64 + i;
            const float4 w4 = w24[(size_t)k * 32];
            const float h0 = hs[0][k], h1 = hs[1][k];
            const float h2 = hs[2][k], h3 = hs[3][k];
            a0.x += h0*w4.x; a0.y += h0*w4.y; a0.z += h0*w4.z; a0.w += h0*w4.w;
            a1.x += h1*w4.x; a1.y += h1*w4.y; a1.z += h1*w4.z; a1.w += h1*w4.w;
            a2.x += h2*w4.x; a2.y += h2*w4.y; a2.z += h2*w4.z; a2.w += h2*w4.w;
            a3.x += h3*w4.x; a3.y += h3*w4.y; a3.z += h3*w4.z; a3.w += h3*w4.w;
        }
        ((float4*)par[kg][0])[pq] = a0;
        ((float4*)par[kg][1])[pq] = a1;
        ((float4*)par[kg][2])[pq] = a2;
        ((float4*)par[kg][3])[pq] = a3;
    }
    __syncthreads();

    float lg0 = b2[p], lg1 = lg0;
    #pragma unroll
    for (int kg = 0; kg < 8; ++kg) {
        lg0 += par[kg][rh][p];
        lg1 += par[kg][rh + 2][p];
    }

    if (mlp == 0) {
        float* __restrict__ dst = nadjT + (size_t)(b * NP + p) * NS + n0;
        dst[rh]     = lg0;
        dst[rh + 2] = lg1;
    } else {
        red[rh][p] = lg0; red[rh + 2][p] = lg1;
        __syncthreads();
        for (int s = 64; s > 0; s >>= 1) {
            if (p < s) {
                red[rh][p]     = fmaxf(red[rh][p],     red[rh][p + s]);
                red[rh + 2][p] = fmaxf(red[rh + 2][p], red[rh + 2][p + s]);
            }
            __syncthreads();
        }
        const float m0 = red[rh][0], m1 = red[rh + 2][0];
        __syncthreads();
        const float e0 = expf(lg0 - m0), e1 = expf(lg1 - m1);
        red[rh][p] = e0; red[rh + 2][p] = e1;
        __syncthreads();
        for (int s = 64; s > 0; s >>= 1) {
            if (p < s) {
                red[rh][p]     += red[rh][p + s];
                red[rh + 2][p] += red[rh + 2][p + s];
            }
            __syncthreads();
        }
        attn[(size_t)(g0 + rh) * NP + p]     = e0 / red[rh][0];
        attn[(size_t)(g0 + rh + 2) * NP + p] = e1 / red[rh + 2][0];
    }
}

__global__ __launch_bounds__(256) void k_fold(
    const float* __restrict__ nadjT, const float* __restrict__ ti,
    const float* __restrict__ w1, const float* __restrict__ b1,
    const float* __restrict__ w2, const float* __restrict__ b2,
    float* __restrict__ tf)
{
    const int b = blockIdx.x >> 7;
    const int p = blockIdx.x & 127;
    const int t = threadIdx.x;
    __shared__ float an[NS];
    __shared__ float w1p[24][48];
    __shared__ float b1s[48];
    __shared__ float w2s[48];

    if (t < 36) {
        ((float4*)an)[t] =
            ((const float4*)(nadjT + (size_t)(b * NP + p) * NS))[t];
    }
    if (t >= 192 && t < 240) {
        const int k = t - 192;
        b1s[k] = b1[k];
        w2s[k] = w2[k];
    }
    for (int i = t; i < 24 * 48; i += 256) {
        const int m = i / 48, k = i - m * 48;
        w1p[m][k] = w1[(2 * m) * 48 + k] + w1[(2 * m + 1) * 48 + k];
    }
    __syncthreads();

    const int d = t;
    const float* __restrict__ tb = ti + (size_t)b * NS * DIM + d;
    float v[24];
    #pragma unroll
    for (int m = 0; m < 24; ++m) v[m] = 0.f;
    #pragma unroll
    for (int y = 0; y < 12; ++y) {
        #pragma unroll
        for (int x = 0; x < 12; ++x) {
            const int n = y * 12 + x;
            const float tv = tb[n * DIM];
            const float a  = an[n];
            v[y]      += a * tv;
            v[12 + x] += a * tv;
        }
    }
    const float c = 0.40824829046386301637f;
    #pragma unroll
    for (int m = 0; m < 24; ++m) v[m] *= c;

    float acc = b2[0];
    for (int k = 0; k < 48; ++k) {
        float tt = b1s[k];
        #pragma unroll
        for (int m = 0; m < 24; ++m) tt += v[m] * w1p[m][k];
        acc += gelu_exact(tt) * w2s[k];
    }
    tf[(size_t)(b * NP + p) * DIM + d] = acc;
}

__global__ __launch_bounds__(256) void k_final(
    const float* __restrict__ attn, const float* __restrict__ tf,
    const float* __restrict__ ti, float4* __restrict__ out)
{
    const int g    = blockIdx.x >> 1;
    const int half = blockIdx.x & 1;
    const int b = g / NS;
    const int n = g % NS;
    const int t = threadIdx.x;
    const int dq = t & 63;
    const int pg = t >> 6;

    __shared__ float  at[NP];
    __shared__ float4 par4[4][64];
    __shared__ float4 rowf[64];

    if (t < NP) at[t] = attn[(size_t)g * NP + t];
    __syncthreads();

    const float4* __restrict__ tp = (const float4*)tf + (size_t)b * NP * 64 + dq;
    float4 acc = make_float4(0.f, 0.f, 0.f, 0.f);
    #pragma unroll 8
    for (int i = 0; i < 32; ++i) {
        const int pp = pg * 32 + i;
        const float  a  = at[pp];
        const float4 tv = tp[(size_t)pp * 64];
        acc.x += a * tv.x; acc.y += a * tv.y;
        acc.z += a * tv.z; acc.w += a * tv.w;
    }
    par4[pg][dq] = acc;
    __syncthreads();

    if (t < 64) {
        float4 s = par4[0][t];
        const float4 s1 = par4[1][t], s2 = par4[2][t], s3 = par4[3][t];
        const float4 tiv = ((const float4*)ti)[(size_t)g * 64 + t];
        s.x += s1.x + s2.x + s3.x + tiv.x;
        s.y += s1.y + s2.y + s3.y + tiv.y;
        s.z += s1.z + s2.z + s3.z + tiv.z;
        s.w += s1.w + s2.w + s3.w + tiv.w;
        rowf[t] = s;
    }
    __syncthreads();

    const int y = n / 12, x = n % 12;
    const int w_lo = (40 * x + 2) / 3;
    const int w_hi = (40 * x + 42) / 3;
    const float4 val = rowf[dq];
    const int h0 = 10 * y + 5 * half;
    for (int h = h0; h < h0 + 5; ++h) {
        float4* __restrict__ orow = out + (size_t)((b * H_OUT + h) * W_OUT) * 64 + dq;
        for (int w = w_lo + pg; w < w_hi; w += 4) {
            orow[(size_t)w * 64] = val;
        }
    }
}

extern "C" void kernel_launch(void* const* d_in, const int* in_sizes, int n_in,
                              void* d_out, int out_size, void* d_ws, size_t ws_size,
                              hipStream_t stream) {
    (void)in_sizes; (void)n_in; (void)out_size; (void)ws_size;
    const float* token_init  = (const float*)d_in[0];  // [4,144,256]
    const float* point_token = (const float*)d_in[1];  // [4,128,256]
    const float* nr_w1 = (const float*)d_in[2];
    const float* nr_b1 = (const float*)d_in[3];
    const float* nr_w2 = (const float*)d_in[4];
    const float* nr_b2 = (const float*)d_in[5];
    const float* na_w1 = (const float*)d_in[6];
    const float* na_b1 = (const float*)d_in[7];
    const float* na_w2 = (const float*)d_in[8];
    const float* na_b2 = (const float*)d_in[9];
    const float* tf_w1 = (const float*)d_in[10];
    const float* tf_b1 = (const float*)d_in[11];
    const float* tf_w2 = (const float*)d_in[12];
    const float* tf_b2 = (const float*)d_in[13];

    float* ws  = (float*)d_ws;
    float* nadjT = ws;                  //  73,728 f  [b*NP+p][n]
    float* attn  = nadjT + NROW * NP;   //  73,728 f
    float* tfb   = attn + NROW * NP;    // 131,072 f
    float* ptT   = tfb + B * NP * DIM;  // 131,072 f  [b][d][p]
    float4* out4 = (float4*)d_out;

    void* args[] = {
        (void*)&token_init, (void*)&point_token,
        (void*)&nr_w1, (void*)&nr_b1, (void*)&nr_w2, (void*)&nr_b2,
        (void*)&na_w1, (void*)&na_b1, (void*)&na_w2, (void*)&na_b2,
        (void*)&tf_w1, (void*)&tf_b1, (void*)&tf_w2, (void*)&tf_b2,
        (void*)&nadjT, (void*)&attn, (void*)&tfb, (void*)&ptT, (void*)&out4
    };
    hipError_t err = hipLaunchCooperativeKernel((const void*)k_all, dim3(256),
                                                dim3(256), args, 0, stream);
    if (err != hipSuccess) {
        (void)hipGetLastError();   // clear sticky error; use verified 4-kernel path
        k_t<<<128, 256, 0, stream>>>(point_token, ptT);
        k_mlp<<<288, 256, 0, stream>>>(token_init, ptT,
                                       nr_w1, nr_b1, nr_w2, nr_b2,
                                       na_w1, na_b1, na_w2, na_b2,
                                       nadjT, attn);
        k_fold<<<B * NP, 256, 0, stream>>>(nadjT, token_init,
                                           tf_w1, tf_b1, tf_w2, tf_b2, tfb);
        k_final<<<NROW * 2, 256, 0, stream>>>(attn, tfb, token_init, out4);
    }
}

// Round 3
// 166.928 us; speedup vs baseline: 2.5553x; 2.5553x over previous
//
#include <hip/hip_runtime.h>
#include <math.h>

// Problem constants (shapes fixed by setup_inputs)
#define B     4
#define DIM   256
#define NP    128   // nPnt
#define NS    144   // 12*12 unique token_init rows per batch
#define HID   512   // 4*nPnt
#define NROW  576   // B*NS
#define H_OUT 120
#define W_OUT 160

__device__ __forceinline__ float gelu_exact(float x) {
    return 0.5f * x * (1.0f + erff(x * 0.70710678118654752440f));
}

// ---------------------------------------------------------------------------
// K_t: transpose point_token -> ptT[b][d][p]. grid = 128 blocks.
// ---------------------------------------------------------------------------
__global__ __launch_bounds__(256) void k_t(
    const float* __restrict__ pt, float* __restrict__ ptT)
{
    const int bid = blockIdx.x;
    const int b   = bid >> 5;
    const int rem = bid & 31;
    const int d0  = (rem >> 2) * 32;
    const int p0  = (rem & 3) * 32;
    const int t   = threadIdx.x;
    __shared__ float tile[32][33];

    #pragma unroll
    for (int i = t; i < 1024; i += 256) {
        const int row = i >> 5, col = i & 31;        // row = p-local, col = d-local
        tile[row][col] = pt[(size_t)(b * NP + p0 + row) * DIM + d0 + col];
    }
    __syncthreads();
    #pragma unroll
    for (int i = t; i < 1024; i += 256) {
        const int row = i >> 5, col = i & 31;        // row = d-local, col = p-local
        ptT[(size_t)(b * DIM + d0 + row) * NP + p0 + col] = tile[col][row];
    }
}

// ---------------------------------------------------------------------------
// K_mlp: fused Q -> layer1 -> layer2 (-> softmax) for BOTH MLPs.
// One block = one (mlp, 4-row tile). grid = 2*144 = 288 blocks, 256 threads.
// Softmax now uses wave shfl reduction (3 barriers instead of ~14).
// ---------------------------------------------------------------------------
__global__ __launch_bounds__(256) void k_mlp(
    const float* __restrict__ ti, const float* __restrict__ ptT,
    const float* __restrict__ nr_w1, const float* __restrict__ nr_b1,
    const float* __restrict__ nr_w2, const float* __restrict__ nr_b2,
    const float* __restrict__ na_w1, const float* __restrict__ na_b1,
    const float* __restrict__ na_w2, const float* __restrict__ na_b2,
    float* __restrict__ nadjT, float* __restrict__ attn)
{
    const int mlp  = blockIdx.x / 144;
    const int tile = blockIdx.x % 144;
    const int g0 = tile * 4;        // 4 consecutive rows, never crosses batch
    const int b  = g0 / NS;
    const int n0 = g0 % NS;
    const int t  = threadIdx.x;

    const float* __restrict__ w1 = mlp ? na_w1 : nr_w1;
    const float* __restrict__ b1 = mlp ? na_b1 : nr_b1;
    const float* __restrict__ w2 = mlp ? na_w2 : nr_w2;
    const float* __restrict__ b2 = mlp ? na_b2 : nr_b2;

    __shared__ float xs[4][DIM];        //  4 KB  ti rows
    __shared__ float parA[2][4][NP];    //  4 KB  Q partials (2 d-halves)
    __shared__ float qs[4][NP];         //  2 KB
    __shared__ float hs[4][HID];        //  8 KB
    __shared__ float par[8][4][NP];     // 16 KB  layer-2 partials
    __shared__ float wred[4][2];        // softmax wave-exchange scratch

    // ---- Stage A: Q[4][128] = ti_rows @ ptT, coalesced ---------------------
    {
        const int r = t >> 6, c = t & 63;
        ((float4*)xs[r])[c] = ((const float4*)ti)[(size_t)(g0 + r) * 64 + c];
    }
    __syncthreads();

    {
        const int pq = t & 31;          // p-quad: p covers pq*4 .. +3
        const int rr = (t >> 5) & 3;    // row
        const int dh = t >> 7;          // d-half
        const float4* __restrict__ pT4 =
            (const float4*)(ptT + (size_t)b * DIM * NP) + pq;
        float4 acc = make_float4(0.f, 0.f, 0.f, 0.f);
        #pragma unroll 8
        for (int d2 = 0; d2 < 128; ++d2) {
            const int d = dh * 128 + d2;
            const float4 v4 = pT4[(size_t)d * 32];
            const float  xv = xs[rr][d];
            acc.x += xv * v4.x; acc.y += xv * v4.y;
            acc.z += xv * v4.z; acc.w += xv * v4.w;
        }
        ((float4*)parA[dh][rr])[pq] = acc;
    }
    __syncthreads();

    const int p  = t & 127;
    const int rh = t >> 7;              // this thread covers rows rh and rh+2
    qs[rh][p]     = (parA[0][rh][p]     + parA[1][rh][p])     * 0.0625f;
    qs[rh + 2][p] = (parA[0][rh + 2][p] + parA[1][rh + 2][p]) * 0.0625f;
    __syncthreads();

    // ---- Stage B: H = gelu(b1 + Q @ w1) -----------------------------------
    {
        const int kq = t & 127;         // k-quad: k0 = kq*4 covers all 512 k
        const int k0 = kq * 4;
        float4 acc0 = *(const float4*)(b1 + k0);
        float4 acc1 = acc0;
        const float* __restrict__ wp = w1 + k0;
        #pragma unroll 16
        for (int pp = 0; pp < NP; ++pp) {
            const float4 w4 = *(const float4*)(wp + (size_t)pp * HID);
            const float q0 = qs[rh][pp];
            const float q1 = qs[rh + 2][pp];
            acc0.x += q0*w4.x; acc0.y += q0*w4.y;
            acc0.z += q0*w4.z; acc0.w += q0*w4.w;
            acc1.x += q1*w4.x; acc1.y += q1*w4.y;
            acc1.z += q1*w4.z; acc1.w += q1*w4.w;
        }
        float4 o0, o1;
        o0.x = gelu_exact(acc0.x); o0.y = gelu_exact(acc0.y);
        o0.z = gelu_exact(acc0.z); o0.w = gelu_exact(acc0.w);
        o1.x = gelu_exact(acc1.x); o1.y = gelu_exact(acc1.y);
        o1.z = gelu_exact(acc1.z); o1.w = gelu_exact(acc1.w);
        ((float4*)hs[rh])[kq]     = o0;
        ((float4*)hs[rh + 2])[kq] = o1;
    }
    __syncthreads();

    // ---- Stage C: logits = b2 + H @ w2 (k split over 8 groups) ------------
    {
        const int pq = t & 31;          // p-quad: p0 = pq*4
        const int p0 = pq * 4;
        const int kg = t >> 5;          // k-group 0..7, 64 k each
        float4 a0 = make_float4(0.f,0.f,0.f,0.f);
        float4 a1 = a0, a2 = a0, a3 = a0;
        const float4* __restrict__ w24 = (const float4*)(w2 + p0);
        #pragma unroll 8
        for (int i = 0; i < 64; ++i) {
            const int k = kg * 64 + i;
            const float4 w4 = w24[(size_t)k * 32];
            const float h0 = hs[0][k], h1 = hs[1][k];
            const float h2 = hs[2][k], h3 = hs[3][k];
            a0.x += h0*w4.x; a0.y += h0*w4.y; a0.z += h0*w4.z; a0.w += h0*w4.w;
            a1.x += h1*w4.x; a1.y += h1*w4.y; a1.z += h1*w4.z; a1.w += h1*w4.w;
            a2.x += h2*w4.x; a2.y += h2*w4.y; a2.z += h2*w4.z; a2.w += h2*w4.w;
            a3.x += h3*w4.x; a3.y += h3*w4.y; a3.z += h3*w4.z; a3.w += h3*w4.w;
        }
        ((float4*)par[kg][0])[pq] = a0;
        ((float4*)par[kg][1])[pq] = a1;
        ((float4*)par[kg][2])[pq] = a2;
        ((float4*)par[kg][3])[pq] = a3;
    }
    __syncthreads();

    // ---- Reduce + emit ----------------------------------------------------
    float lg0 = b2[p], lg1 = lg0;
    #pragma unroll
    for (int kg = 0; kg < 8; ++kg) {
        lg0 += par[kg][rh][p];
        lg1 += par[kg][rh + 2][p];
    }

    if (mlp == 0) {
        float* __restrict__ dst = nadjT + (size_t)(b * NP + p) * NS + n0;
        dst[rh]     = lg0;
        dst[rh + 2] = lg1;
    } else {
        // Softmax over p (128 values = 2 waves per row). Wave shfl reduce +
        // one LDS exchange between the wave pair. Rows: rh -> waves {0,1},
        // rh+0? mapping: t in [rh*128, rh*128+128) => waves {2rh, 2rh+1}.
        const int wid   = t >> 6;       // 0..3
        const int wpair = wid ^ 1;      // other wave of the same row-pair
        float m0 = lg0, m1 = lg1;
        #pragma unroll
        for (int off = 32; off > 0; off >>= 1) {
            m0 = fmaxf(m0, __shfl_xor(m0, off));
            m1 = fmaxf(m1, __shfl_xor(m1, off));
        }
        if ((t & 63) == 0) { wred[wid][0] = m0; wred[wid][1] = m1; }
        __syncthreads();
        m0 = fmaxf(m0, wred[wpair][0]);
        m1 = fmaxf(m1, wred[wpair][1]);

        const float e0 = expf(lg0 - m0), e1 = expf(lg1 - m1);
        float s0 = e0, s1 = e1;
        #pragma unroll
        for (int off = 32; off > 0; off >>= 1) {
            s0 += __shfl_xor(s0, off);
            s1 += __shfl_xor(s1, off);
        }
        __syncthreads();   // all reads of wred (max) done before overwrite
        if ((t & 63) == 0) { wred[wid][0] = s0; wred[wid][1] = s1; }
        __syncthreads();
        s0 += wred[wpair][0];
        s1 += wred[wpair][1];

        attn[(size_t)(g0 + rh) * NP + p]     = e0 / s0;
        attn[(size_t)(g0 + rh + 2) * NP + p] = e1 / s1;
    }
}

// ---------------------------------------------------------------------------
// K_fold: fused (node_w/node_h einsums + tf MLP). grid = 4*128 = 512 blocks.
// ---------------------------------------------------------------------------
__global__ __launch_bounds__(256) void k_fold(
    const float* __restrict__ nadjT, const float* __restrict__ ti,
    const float* __restrict__ w1, const float* __restrict__ b1,
    const float* __restrict__ w2, const float* __restrict__ b2,
    float* __restrict__ tf)
{
    const int b = blockIdx.x >> 7;
    const int p = blockIdx.x & 127;
    const int t = threadIdx.x;
    __shared__ float an[NS];
    __shared__ float w1p[24][48];
    __shared__ float b1s[48];
    __shared__ float w2s[48];

    if (t < 36) {   // 144 floats = 36 float4, coalesced from nadjT row
        ((float4*)an)[t] =
            ((const float4*)(nadjT + (size_t)(b * NP + p) * NS))[t];
    }
    if (t >= 192 && t < 240) {
        const int k = t - 192;
        b1s[k] = b1[k];
        w2s[k] = w2[k];
    }
    for (int i = t; i < 24 * 48; i += 256) {
        const int m = i / 48, k = i - m * 48;
        w1p[m][k] = w1[(2 * m) * 48 + k] + w1[(2 * m + 1) * 48 + k];
    }
    __syncthreads();

    const int d = t;
    const float* __restrict__ tb = ti + (size_t)b * NS * DIM + d;
    float v[24];
    #pragma unroll
    for (int m = 0; m < 24; ++m) v[m] = 0.f;
    #pragma unroll
    for (int y = 0; y < 12; ++y) {
        #pragma unroll
        for (int x = 0; x < 12; ++x) {
            const int n = y * 12 + x;
            const float tv = tb[n * DIM];
            const float a  = an[n];
            v[y]      += a * tv;   // node_w: m=y, j=x
            v[12 + x] += a * tv;   // node_h: m=12+x, j=y
        }
    }
    const float c = 0.40824829046386301637f;  // 2/sqrt(24)
    #pragma unroll
    for (int m = 0; m < 24; ++m) v[m] *= c;

    float acc = b2[0];
    for (int k = 0; k < 48; ++k) {
        float tt = b1s[k];
        #pragma unroll
        for (int m = 0; m < 24; ++m) tt += v[m] * w1p[m][k];
        acc += gelu_exact(tt) * w2s[k];
    }
    tf[(size_t)(b * NP + p) * DIM + d] = acc;
}

// ---------------------------------------------------------------------------
// K_final (merged): one block per output row g. row[d] = ti[g][d] +
// sum_p attn[g][p]*tf[b,p,d]; broadcast-scatter to out[b,h,w,:].
// grid = 576. (Logic identical to the correctness-verified coop phase 3.)
// ---------------------------------------------------------------------------
__global__ __launch_bounds__(256) void k_final(
    const float* __restrict__ attn, const float* __restrict__ tf,
    const float* __restrict__ ti, float4* __restrict__ out)
{
    const int g = blockIdx.x;
    const int b = g / NS;
    const int n = g % NS;
    const int t = threadIdx.x;
    const int dq = t & 63;
    const int pg = t >> 6;

    __shared__ float  at[NP];
    __shared__ float4 par4[4][64];
    __shared__ float4 rowf[64];

    if (t < NP) at[t] = attn[(size_t)g * NP + t];
    __syncthreads();

    const float4* __restrict__ tp = (const float4*)tf + (size_t)b * NP * 64 + dq;
    float4 acc = make_float4(0.f, 0.f, 0.f, 0.f);
    #pragma unroll 16
    for (int i = 0; i < 32; ++i) {
        const int pp = pg * 32 + i;
        const float  a  = at[pp];
        const float4 tv = tp[(size_t)pp * 64];
        acc.x += a * tv.x; acc.y += a * tv.y;
        acc.z += a * tv.z; acc.w += a * tv.w;
    }
    par4[pg][dq] = acc;
    __syncthreads();

    if (t < 64) {
        float4 s = par4[0][t];
        const float4 s1 = par4[1][t], s2 = par4[2][t], s3 = par4[3][t];
        const float4 tiv = ((const float4*)ti)[(size_t)g * 64 + t];
        s.x += s1.x + s2.x + s3.x + tiv.x;
        s.y += s1.y + s2.y + s3.y + tiv.y;
        s.z += s1.z + s2.z + s3.z + tiv.z;
        s.w += s1.w + s2.w + s3.w + tiv.w;
        rowf[t] = s;
    }
    __syncthreads();

    // scatter: src(h,w) = (h/10)*12 + (3w)/40 == n  <=>  h in [10y,10y+10),
    // w in [ceil(40x/3), ceil(40(x+1)/3)) where n = y*12+x.
    const int y = n / 12, x = n % 12;
    const int w_lo = (40 * x + 2) / 3;
    const int w_hi = (40 * x + 42) / 3;
    const float4 val = rowf[dq];
    const int h0 = 10 * y;
    for (int h = h0; h < h0 + 10; ++h) {
        float4* __restrict__ orow = out + (size_t)((b * H_OUT + h) * W_OUT) * 64 + dq;
        for (int w = w_lo + pg; w < w_hi; w += 4) {
            orow[(size_t)w * 64] = val;
        }
    }
}

extern "C" void kernel_launch(void* const* d_in, const int* in_sizes, int n_in,
                              void* d_out, int out_size, void* d_ws, size_t ws_size,
                              hipStream_t stream) {
    (void)in_sizes; (void)n_in; (void)out_size; (void)ws_size;
    const float* token_init  = (const float*)d_in[0];  // [4,144,256]
    const float* point_token = (const float*)d_in[1];  // [4,128,256]
    const float* nr_w1 = (const float*)d_in[2];
    const float* nr_b1 = (const float*)d_in[3];
    const float* nr_w2 = (const float*)d_in[4];
    const float* nr_b2 = (const float*)d_in[5];
    const float* na_w1 = (const float*)d_in[6];
    const float* na_b1 = (const float*)d_in[7];
    const float* na_w2 = (const float*)d_in[8];
    const float* na_b2 = (const float*)d_in[9];
    const float* tf_w1 = (const float*)d_in[10];
    const float* tf_b1 = (const float*)d_in[11];
    const float* tf_w2 = (const float*)d_in[12];
    const float* tf_b2 = (const float*)d_in[13];

    float* out = (float*)d_out;
    float* ws  = (float*)d_ws;
    float* nadjT = ws;                  //  73,728 f  [b*NP+p][n]
    float* attn  = nadjT + NROW * NP;   //  73,728 f
    float* tf    = attn + NROW * NP;    // 131,072 f
    float* ptT   = tf + B * NP * DIM;   // 131,072 f  [b][d][p]  (~1.6 MB total)

    k_t<<<128, 256, 0, stream>>>(point_token, ptT);
    k_mlp<<<288, 256, 0, stream>>>(token_init, ptT,
                                   nr_w1, nr_b1, nr_w2, nr_b2,
                                   na_w1, na_b1, na_w2, na_b2,
                                   nadjT, attn);
    k_fold<<<B * NP, 256, 0, stream>>>(nadjT, token_init,
                                       tf_w1, tf_b1, tf_w2, tf_b2, tf);
    k_final<<<NROW, 256, 0, stream>>>(attn, tf, token_init, (float4*)out);
}

// Round 4
// 160.674 us; speedup vs baseline: 2.6547x; 1.0389x over previous
//
#include <hip/hip_runtime.h>
#include <math.h>

// Problem constants (shapes fixed by setup_inputs)
#define B     4
#define DIM   256
#define NP    128   // nPnt
#define NS    144   // 12*12 unique token_init rows per batch
#define HID   512   // 4*nPnt
#define NROW  576   // B*NS
#define H_OUT 120
#define W_OUT 160

__device__ __forceinline__ float gelu_exact(float x) {
    return 0.5f * x * (1.0f + erff(x * 0.70710678118654752440f));
}

// ---------------------------------------------------------------------------
// K_t: blocks 0..127: transpose point_token -> ptT[b][d][p].
// Block 128: precompute folded tf-MLP layer-1 weights w1p[24][48] into ws
// (w1p[m][k] = tf_w1[2m][k] + tf_w1[2m+1][k]) so k_fold can read them as
// wave-uniform scalar loads. grid = 129 blocks.
// ---------------------------------------------------------------------------
__global__ __launch_bounds__(256) void k_t(
    const float* __restrict__ pt, const float* __restrict__ tf_w1,
    float* __restrict__ ptT, float* __restrict__ w1pg)
{
    const int bid = blockIdx.x;
    const int t   = threadIdx.x;

    if (bid == 128) {
        for (int i = t; i < 24 * 48; i += 256) {
            const int m = i / 48, k = i - m * 48;
            w1pg[i] = tf_w1[(2 * m) * 48 + k] + tf_w1[(2 * m + 1) * 48 + k];
        }
        return;
    }

    const int b   = bid >> 5;
    const int rem = bid & 31;
    const int d0  = (rem >> 2) * 32;
    const int p0  = (rem & 3) * 32;
    __shared__ float tile[32][33];

    #pragma unroll
    for (int i = t; i < 1024; i += 256) {
        const int row = i >> 5, col = i & 31;        // row = p-local, col = d-local
        tile[row][col] = pt[(size_t)(b * NP + p0 + row) * DIM + d0 + col];
    }
    __syncthreads();
    #pragma unroll
    for (int i = t; i < 1024; i += 256) {
        const int row = i >> 5, col = i & 31;        // row = d-local, col = p-local
        ptT[(size_t)(b * DIM + d0 + row) * NP + p0 + col] = tile[col][row];
    }
}

// ---------------------------------------------------------------------------
// K_mlp: fused Q -> layer1 -> layer2 (-> softmax) for BOTH MLPs.
// One block = one (mlp, 4-row tile). grid = 2*144 = 288 blocks, 256 threads.
// Stage A: thread (d-group, p-quad) holds 4 row-accumulators so the ptT
// panel is streamed ONCE (128 KB/block from L2) instead of 4x.
// ---------------------------------------------------------------------------
__global__ __launch_bounds__(256) void k_mlp(
    const float* __restrict__ ti, const float* __restrict__ ptT,
    const float* __restrict__ nr_w1, const float* __restrict__ nr_b1,
    const float* __restrict__ nr_w2, const float* __restrict__ nr_b2,
    const float* __restrict__ na_w1, const float* __restrict__ na_b1,
    const float* __restrict__ na_w2, const float* __restrict__ na_b2,
    float* __restrict__ nadjT, float* __restrict__ attn)
{
    const int mlp  = blockIdx.x / 144;
    const int tile = blockIdx.x % 144;
    const int g0 = tile * 4;        // 4 consecutive rows, never crosses batch
    const int b  = g0 / NS;
    const int n0 = g0 % NS;
    const int t  = threadIdx.x;

    const float* __restrict__ w1 = mlp ? na_w1 : nr_w1;
    const float* __restrict__ b1 = mlp ? na_b1 : nr_b1;
    const float* __restrict__ w2 = mlp ? na_w2 : nr_w2;
    const float* __restrict__ b2 = mlp ? na_b2 : nr_b2;

    __shared__ float xs[4][DIM];        //  4 KB  ti rows
    __shared__ float parA[8][4][NP];    // 16 KB  Q partials (8 d-groups)
    __shared__ float qs[4][NP];         //  2 KB
    __shared__ float hs[4][HID];        //  8 KB
    __shared__ float par[8][4][NP];     // 16 KB  layer-2 partials
    __shared__ float wred[4][2];        // softmax wave-exchange scratch

    // ---- Stage A: Q[4][128] = ti_rows @ ptT, single pass over ptT ---------
    {
        const int r = t >> 6, c = t & 63;
        ((float4*)xs[r])[c] = ((const float4*)ti)[(size_t)(g0 + r) * 64 + c];
    }
    __syncthreads();

    {
        const int pq = t & 31;          // p-quad: p covers pq*4 .. +3
        const int dg = t >> 5;          // d-group 0..7 (32 d's each)
        const float4* __restrict__ pT4 =
            (const float4*)(ptT + (size_t)b * DIM * NP) + pq;
        float4 a0 = make_float4(0.f,0.f,0.f,0.f);
        float4 a1 = a0, a2 = a0, a3 = a0;
        #pragma unroll 8
        for (int d2 = 0; d2 < 32; ++d2) {
            const int d = dg * 32 + d2;
            const float4 v4 = pT4[(size_t)d * 32];
            const float x0 = xs[0][d], x1 = xs[1][d];
            const float x2 = xs[2][d], x3 = xs[3][d];
            a0.x += x0*v4.x; a0.y += x0*v4.y; a0.z += x0*v4.z; a0.w += x0*v4.w;
            a1.x += x1*v4.x; a1.y += x1*v4.y; a1.z += x1*v4.z; a1.w += x1*v4.w;
            a2.x += x2*v4.x; a2.y += x2*v4.y; a2.z += x2*v4.z; a2.w += x2*v4.w;
            a3.x += x3*v4.x; a3.y += x3*v4.y; a3.z += x3*v4.z; a3.w += x3*v4.w;
        }
        ((float4*)parA[dg][0])[pq] = a0;
        ((float4*)parA[dg][1])[pq] = a1;
        ((float4*)parA[dg][2])[pq] = a2;
        ((float4*)parA[dg][3])[pq] = a3;
    }
    __syncthreads();

    const int p  = t & 127;
    const int rh = t >> 7;              // this thread covers rows rh and rh+2
    {
        float q0 = 0.f, q1 = 0.f;
        #pragma unroll
        for (int dg = 0; dg < 8; ++dg) {
            q0 += parA[dg][rh][p];
            q1 += parA[dg][rh + 2][p];
        }
        qs[rh][p]     = q0 * 0.0625f;
        qs[rh + 2][p] = q1 * 0.0625f;
    }
    __syncthreads();

    // ---- Stage B: H = gelu(b1 + Q @ w1) -----------------------------------
    {
        const int kq = t & 127;         // k-quad: k0 = kq*4 covers all 512 k
        const int k0 = kq * 4;
        float4 acc0 = *(const float4*)(b1 + k0);
        float4 acc1 = acc0;
        const float* __restrict__ wp = w1 + k0;
        #pragma unroll 16
        for (int pp = 0; pp < NP; ++pp) {
            const float4 w4 = *(const float4*)(wp + (size_t)pp * HID);
            const float q0 = qs[rh][pp];
            const float q1 = qs[rh + 2][pp];
            acc0.x += q0*w4.x; acc0.y += q0*w4.y;
            acc0.z += q0*w4.z; acc0.w += q0*w4.w;
            acc1.x += q1*w4.x; acc1.y += q1*w4.y;
            acc1.z += q1*w4.z; acc1.w += q1*w4.w;
        }
        float4 o0, o1;
        o0.x = gelu_exact(acc0.x); o0.y = gelu_exact(acc0.y);
        o0.z = gelu_exact(acc0.z); o0.w = gelu_exact(acc0.w);
        o1.x = gelu_exact(acc1.x); o1.y = gelu_exact(acc1.y);
        o1.z = gelu_exact(acc1.z); o1.w = gelu_exact(acc1.w);
        ((float4*)hs[rh])[kq]     = o0;
        ((float4*)hs[rh + 2])[kq] = o1;
    }
    __syncthreads();

    // ---- Stage C: logits = b2 + H @ w2 (k split over 8 groups) ------------
    {
        const int pq = t & 31;          // p-quad: p0 = pq*4
        const int p0 = pq * 4;
        const int kg = t >> 5;          // k-group 0..7, 64 k each
        float4 a0 = make_float4(0.f,0.f,0.f,0.f);
        float4 a1 = a0, a2 = a0, a3 = a0;
        const float4* __restrict__ w24 = (const float4*)(w2 + p0);
        #pragma unroll 8
        for (int i = 0; i < 64; ++i) {
            const int k = kg * 64 + i;
            const float4 w4 = w24[(size_t)k * 32];
            const float h0 = hs[0][k], h1 = hs[1][k];
            const float h2 = hs[2][k], h3 = hs[3][k];
            a0.x += h0*w4.x; a0.y += h0*w4.y; a0.z += h0*w4.z; a0.w += h0*w4.w;
            a1.x += h1*w4.x; a1.y += h1*w4.y; a1.z += h1*w4.z; a1.w += h1*w4.w;
            a2.x += h2*w4.x; a2.y += h2*w4.y; a2.z += h2*w4.z; a2.w += h2*w4.w;
            a3.x += h3*w4.x; a3.y += h3*w4.y; a3.z += h3*w4.z; a3.w += h3*w4.w;
        }
        ((float4*)par[kg][0])[pq] = a0;
        ((float4*)par[kg][1])[pq] = a1;
        ((float4*)par[kg][2])[pq] = a2;
        ((float4*)par[kg][3])[pq] = a3;
    }
    __syncthreads();

    // ---- Reduce + emit ----------------------------------------------------
    float lg0 = b2[p], lg1 = lg0;
    #pragma unroll
    for (int kg = 0; kg < 8; ++kg) {
        lg0 += par[kg][rh][p];
        lg1 += par[kg][rh + 2][p];
    }

    if (mlp == 0) {
        float* __restrict__ dst = nadjT + (size_t)(b * NP + p) * NS + n0;
        dst[rh]     = lg0;
        dst[rh + 2] = lg1;
    } else {
        // Softmax over p (128 values = 2 waves per row): wave shfl reduce +
        // one LDS exchange between the wave pair.
        const int wid   = t >> 6;       // 0..3
        const int wpair = wid ^ 1;      // other wave of the same row
        float m0 = lg0, m1 = lg1;
        #pragma unroll
        for (int off = 32; off > 0; off >>= 1) {
            m0 = fmaxf(m0, __shfl_xor(m0, off));
            m1 = fmaxf(m1, __shfl_xor(m1, off));
        }
        if ((t & 63) == 0) { wred[wid][0] = m0; wred[wid][1] = m1; }
        __syncthreads();
        m0 = fmaxf(m0, wred[wpair][0]);
        m1 = fmaxf(m1, wred[wpair][1]);

        const float e0 = expf(lg0 - m0), e1 = expf(lg1 - m1);
        float s0 = e0, s1 = e1;
        #pragma unroll
        for (int off = 32; off > 0; off >>= 1) {
            s0 += __shfl_xor(s0, off);
            s1 += __shfl_xor(s1, off);
        }
        __syncthreads();   // all reads of wred (max) done before overwrite
        if ((t & 63) == 0) { wred[wid][0] = s0; wred[wid][1] = s1; }
        __syncthreads();
        s0 += wred[wpair][0];
        s1 += wred[wpair][1];

        attn[(size_t)(g0 + rh) * NP + p]     = e0 / s0;
        attn[(size_t)(g0 + rh + 2) * NP + p] = e1 / s1;
    }
}

// ---------------------------------------------------------------------------
// K_fold: fused (node_w/node_h einsums + tf MLP). grid = 4*128 = 512 blocks.
// All weight/adjacency operands (an row, w1p, b1, w2, b2) are read directly
// from global with wave-uniform indices -> compiler scalarizes to s_load
// through K$; the inner loop is pure v_fmac with SGPR operands. No LDS.
// ---------------------------------------------------------------------------
__global__ __launch_bounds__(256) void k_fold(
    const float* __restrict__ nadjT, const float* __restrict__ ti,
    const float* __restrict__ w1p,   // precomputed [24][48] (k_t block 128)
    const float* __restrict__ b1, const float* __restrict__ w2,
    const float* __restrict__ b2, float* __restrict__ tf)
{
    const int b = blockIdx.x >> 7;
    const int p = blockIdx.x & 127;
    const int t = threadIdx.x;

    const float* __restrict__ an = nadjT + (size_t)(b * NP + p) * NS; // uniform
    const int d = t;
    const float* __restrict__ tb = ti + (size_t)b * NS * DIM + d;

    float v[24];
    #pragma unroll
    for (int m = 0; m < 24; ++m) v[m] = 0.f;
    #pragma unroll
    for (int y = 0; y < 12; ++y) {
        #pragma unroll
        for (int x = 0; x < 12; ++x) {
            const int n = y * 12 + x;
            const float tv = tb[n * DIM];   // vector, lane-coalesced
            const float a  = an[n];         // uniform -> scalar load
            v[y]      += a * tv;   // node_w: m=y, j=x
            v[12 + x] += a * tv;   // node_h: m=12+x, j=y
        }
    }
    const float c = 0.40824829046386301637f;  // 2/sqrt(24)
    #pragma unroll
    for (int m = 0; m < 24; ++m) v[m] *= c;

    float acc = b2[0];
    for (int k = 0; k < 48; ++k) {
        float tt = b1[k];                       // uniform
        #pragma unroll
        for (int m = 0; m < 24; ++m) tt += v[m] * w1p[m * 48 + k];  // uniform
        acc += gelu_exact(tt) * w2[k];          // uniform
    }
    tf[(size_t)(b * NP + p) * DIM + d] = acc;
}

// ---------------------------------------------------------------------------
// K_final (merged): one block per output row g. row[d] = ti[g][d] +
// sum_p attn[g][p]*tf[b,p,d]; broadcast-scatter to out[b,h,w,:]. grid = 576.
// ---------------------------------------------------------------------------
__global__ __launch_bounds__(256) void k_final(
    const float* __restrict__ attn, const float* __restrict__ tf,
    const float* __restrict__ ti, float4* __restrict__ out)
{
    const int g = blockIdx.x;
    const int b = g / NS;
    const int n = g % NS;
    const int t = threadIdx.x;
    const int dq = t & 63;
    const int pg = t >> 6;

    __shared__ float  at[NP];
    __shared__ float4 par4[4][64];
    __shared__ float4 rowf[64];

    if (t < NP) at[t] = attn[(size_t)g * NP + t];
    __syncthreads();

    const float4* __restrict__ tp = (const float4*)tf + (size_t)b * NP * 64 + dq;
    float4 acc = make_float4(0.f, 0.f, 0.f, 0.f);
    #pragma unroll 16
    for (int i = 0; i < 32; ++i) {
        const int pp = pg * 32 + i;
        const float  a  = at[pp];
        const float4 tv = tp[(size_t)pp * 64];
        acc.x += a * tv.x; acc.y += a * tv.y;
        acc.z += a * tv.z; acc.w += a * tv.w;
    }
    par4[pg][dq] = acc;
    __syncthreads();

    if (t < 64) {
        float4 s = par4[0][t];
        const float4 s1 = par4[1][t], s2 = par4[2][t], s3 = par4[3][t];
        const float4 tiv = ((const float4*)ti)[(size_t)g * 64 + t];
        s.x += s1.x + s2.x + s3.x + tiv.x;
        s.y += s1.y + s2.y + s3.y + tiv.y;
        s.z += s1.z + s2.z + s3.z + tiv.z;
        s.w += s1.w + s2.w + s3.w + tiv.w;
        rowf[t] = s;
    }
    __syncthreads();

    // scatter: src(h,w) = (h/10)*12 + (3w)/40 == n  <=>  h in [10y,10y+10),
    // w in [ceil(40x/3), ceil(40(x+1)/3)) where n = y*12+x.
    const int y = n / 12, x = n % 12;
    const int w_lo = (40 * x + 2) / 3;
    const int w_hi = (40 * x + 42) / 3;
    const float4 val = rowf[dq];
    const int h0 = 10 * y;
    for (int h = h0; h < h0 + 10; ++h) {
        float4* __restrict__ orow = out + (size_t)((b * H_OUT + h) * W_OUT) * 64 + dq;
        for (int w = w_lo + pg; w < w_hi; w += 4) {
            orow[(size_t)w * 64] = val;
        }
    }
}

extern "C" void kernel_launch(void* const* d_in, const int* in_sizes, int n_in,
                              void* d_out, int out_size, void* d_ws, size_t ws_size,
                              hipStream_t stream) {
    (void)in_sizes; (void)n_in; (void)out_size; (void)ws_size;
    const float* token_init  = (const float*)d_in[0];  // [4,144,256]
    const float* point_token = (const float*)d_in[1];  // [4,128,256]
    const float* nr_w1 = (const float*)d_in[2];
    const float* nr_b1 = (const float*)d_in[3];
    const float* nr_w2 = (const float*)d_in[4];
    const float* nr_b2 = (const float*)d_in[5];
    const float* na_w1 = (const float*)d_in[6];
    const float* na_b1 = (const float*)d_in[7];
    const float* na_w2 = (const float*)d_in[8];
    const float* na_b2 = (const float*)d_in[9];
    const float* tf_w1 = (const float*)d_in[10];
    const float* tf_b1 = (const float*)d_in[11];
    const float* tf_w2 = (const float*)d_in[12];
    const float* tf_b2 = (const float*)d_in[13];

    float* out = (float*)d_out;
    float* ws  = (float*)d_ws;
    float* nadjT = ws;                  //  73,728 f  [b*NP+p][n]
    float* attn  = nadjT + NROW * NP;   //  73,728 f
    float* tf    = attn + NROW * NP;    // 131,072 f
    float* ptT   = tf + B * NP * DIM;   // 131,072 f  [b][d][p]
    float* w1pg  = ptT + B * DIM * NP;  //   1,152 f  [24][48]  (~1.6 MB total)

    k_t<<<129, 256, 0, stream>>>(point_token, tf_w1, ptT, w1pg);
    k_mlp<<<288, 256, 0, stream>>>(token_init, ptT,
                                   nr_w1, nr_b1, nr_w2, nr_b2,
                                   na_w1, na_b1, na_w2, na_b2,
                                   nadjT, attn);
    k_fold<<<B * NP, 256, 0, stream>>>(nadjT, token_init, w1pg,
                                       tf_b1, tf_w2, tf_b2, tf);
    k_final<<<NROW, 256, 0, stream>>>(attn, tf, token_init, (float4*)out);
}